// Round 9
// baseline (268.616 us; speedup 1.0000x reference)
//
#include <hip/hip_runtime.h>
#include <cstdint>

#define BB 2
#define NN 16384
#define MM 4096
#define CF 256
#define CT 128
#define CP 64
#define NSEG 16
#define SEGSZ 256

// ================= kernel 0: counting-sort refs & queries by x =================
// Refs: sorted into pre-doubled float4 (2x,2y,2z,rr) + original-index array.
// Queries: index array sorted by x (so a wave's 8 queries share an x-band).
// Per-segment conservative x-ranges from analytic bin edges (outer edges
// -> +-inf so clamped outliers can never be wrongly skipped). Within-bin
// scatter order is atomic-nondeterministic — harmless: the knn network is
// fully lexicographic in (d, j), so the output is order-independent.
__global__ __launch_bounds__(512) void sort_kernel(
    const float* __restrict__ coords,      // [B,N,3]
    const float* __restrict__ ref_coords,  // [B,M,3]
    float4* __restrict__ sR,               // [B,M] sorted pre-doubled refs
    int*    __restrict__ sJ,               // [B,M] original ref index
    int*    __restrict__ sQ,               // [B,N] query order
    float2* __restrict__ segB)             // [B,16] conservative seg x-range
{
#pragma clang fp contract(off)
    __shared__ int hist[256];
    __shared__ int base_[257];
    const int tid = threadIdx.x;
    const int b   = blockIdx.y;
    const bool doRefs = (blockIdx.x == 0);
    const int count = doRefs ? MM : NN;
    const float* src = doRefs ? (ref_coords + (size_t)b * MM * 3)
                              : (coords     + (size_t)b * NN * 3);

    if (tid < 256) hist[tid] = 0;
    __syncthreads();
    for (int e = tid; e < count; e += 512) {
        const float x = src[3 * e];
        int bin = (int)((x + 4.5f) * (256.0f / 9.0f));
        bin = bin < 0 ? 0 : (bin > 255 ? 255 : bin);
        atomicAdd(&hist[bin], 1);
    }
    __syncthreads();
    if (tid == 0) {
        int acc = 0;
        for (int k = 0; k < 256; ++k) { base_[k] = acc; acc += hist[k]; }
        base_[256] = acc;
    }
    __syncthreads();
    if (tid < 256) hist[tid] = base_[tid];   // reuse as scatter cursors
    __syncthreads();
    for (int e = tid; e < count; e += 512) {
        const float x = src[3 * e];
        int bin = (int)((x + 4.5f) * (256.0f / 9.0f));
        bin = bin < 0 ? 0 : (bin > 255 ? 255 : bin);
        const int pos = atomicAdd(&hist[bin], 1);
        if (doRefs) {
            const float y = src[3 * e + 1];
            const float z = src[3 * e + 2];
            // identical math to the proven staging: pre-doubled xyz (exact),
            // rr from ORIGINAL coords in numpy sum order
            sR[(size_t)b * MM + pos] = make_float4(x + x, y + y, z + z,
                                                   (x * x + y * y) + z * z);
            sJ[(size_t)b * MM + pos] = e;
        } else {
            sQ[(size_t)b * NN + pos] = e;
        }
    }
    __syncthreads();
    if (doRefs && tid == 0) {
        // conservative per-segment x-range from bin edges
        for (int sg = 0; sg < NSEG; ++sg) {
            const int plo = sg * SEGSZ, phi = plo + SEGSZ - 1;
            int blo = 0; while (base_[blo + 1] <= plo) ++blo;
            int bhi = blo; while (base_[bhi + 1] <= phi) ++bhi;
            float xlo = (blo == 0)   ? -1e30f : (blo * (9.0f / 256.0f) - 4.5f);
            float xhi = (bhi == 255) ?  1e30f : ((bhi + 1) * (9.0f / 256.0f) - 4.5f);
            segB[b * NSEG + sg] = make_float2(xlo, xhi);
        }
    }
}

// ======================= kernel 1: 3-NN (pruned scan) =======================
// R2's proven scan machinery (8 sub-lanes/query, __any-gated exact update,
// tau pruning, 32-iter cadence) operating on x-SORTED refs with whole-segment
// skipping. Wave's 8 queries are sorted-adjacent -> shared x-band -> a 256-ref
// segment is skipped iff ALL lanes prove dxmin^2 - 1e-4 > thr (safe: d2 >=
// dx2 mathematically; 1e-4 >> fp error of dd at these magnitudes; thr=INF
// until a lane's top-3 fills, so >=3 candidates always examined). Permuted
// scan order => index updates are LEXICOGRAPHIC in (d, j) and the gate is
// dd <= thr (a dd==d2v tie with smaller j must enter) -> output provably
// identical to stable top_k regardless of within-bin scatter order. Value
// network (min/med3) is order-independent as-is.
#define TPB1 512

__global__ __launch_bounds__(TPB1, 4) void knn_kernel(
    const float* __restrict__ coords,      // [B,N,3]
    const float4* __restrict__ sR,         // [B,M] sorted refs
    const int*   __restrict__ sJ,          // [B,M] orig ref idx
    const int*   __restrict__ sQ,          // [B,N] query order
    const float2* __restrict__ segB,       // [B,16]
    int4* __restrict__ wsI,                // [B,N] {i0,i1,i2,-}
    float4* __restrict__ wsW)              // [B,N] {w0,w1,w2,-}
{
#pragma clang fp contract(off)
    __shared__ float4 sref[MM];      // 64 KB
    __shared__ int    sjj[MM];       // 16 KB

    const int tid = threadIdx.x;
    const int b   = blockIdx.y;

    for (int e = tid; e < MM; e += TPB1) {
        sref[e] = sR[(size_t)b * MM + e];
        sjj[e]  = sJ[(size_t)b * MM + e];
    }
    __syncthreads();

    const int pl = tid >> 3;            // query-in-block 0..63 (sorted order)
    const int s  = tid & 7;             // sub-lane 0..7
    const int p  = blockIdx.x * 64 + pl;
    const int qi = sQ[(size_t)b * NN + p];   // original query index

    const float* cp = coords + ((size_t)b * NN + qi) * 3;
    const float cx = cp[0];
    const float cy = cp[1];
    const float cz = cp[2];
    const float cc = (cx * cx + cy * cy) + cz * cz;   // numpy sum order

    float d0 = INFINITY, d1 = INFINITY, d2v = INFINITY;
    int   i0 = 0, i1 = 0, i2 = 0;
    float tau = INFINITY;               // 8-lane pruning threshold
    float thr = INFINITY;               // min(d2v, tau)

    // wave-uniform start segment from a representative query x
    const float xr = __shfl(cx, 32, 64);
    const float2* sb = segB + b * NSEG;
    int seg0 = 0;
    #pragma unroll
    for (int k = 1; k < NSEG; ++k) seg0 += (sb[k].x <= xr) ? 1 : 0;

    // visit segments center-outward: 0, +1, -1, +2, -2, ...
    for (int t = 0; t < 2 * NSEG - 1; ++t) {
        const int o   = (t & 1) ? ((t >> 1) + 1) : -(t >> 1);
        const int seg = seg0 + o;
        if (seg < 0 || seg >= NSEG) continue;

        const float2 be = sb[seg];
        const float dxm = fmaxf(0.0f, fmaxf(be.x - cx, cx - be.y));
        if (__all(dxm * dxm - 1e-4f > thr)) continue;   // provably dead segment

        const int ebase = seg * SEGSZ + s;
        #pragma unroll 4
        for (int k = 0; k < 32; ++k) {
            const int e = ebase + (k << 3);
            const float4 r = sref[e];
            // dot2 == 2*((cx*rx + cy*ry) + cz*rz) bit-exactly (pre-doubled)
            const float dot2 = (cx * r.x + cy * r.y) + cz * r.z;
            const float dd   = (cc + r.w) - dot2;        // == numpy d2
            if (__any(dd <= thr)) {
                const int j = sjj[e];
                // lexicographic (d, j): permuted order, lower j wins ties
                const bool l0 = (dd < d0)  || (dd == d0  && j < i0);
                const bool l1 = (dd < d1)  || (dd == d1  && j < i1);
                const bool l2 = (dd < d2v) || (dd == d2v && j < i2);
                i2 = l2 ? (l1 ? i1 : j) : i2;
                i1 = l1 ? (l0 ? i0 : j) : i1;
                i0 = l0 ? j : i0;
                const float n2  = __builtin_amdgcn_fmed3f(dd, d1, d2v);
                const float n1  = __builtin_amdgcn_fmed3f(dd, d0, d1);
                const float nv0 = fminf(dd, d0);
                d2v = n2; d1 = n1; d0 = nv0;
                thr = fminf(d2v, tau);
            }
        }
        // refresh tau = min of this query's 8 sub-lanes' d2v (R2 cadence)
        float tt = d2v;
        tt = fminf(tt, __shfl_xor(tt, 1, 64));
        tt = fminf(tt, __shfl_xor(tt, 2, 64));
        tt = fminf(tt, __shfl_xor(tt, 4, 64));
        tau = tt;
        thr = fminf(d2v, tau);
    }

    // lexicographic (d, idx) merge across the 8 sub-lanes (proven)
    auto ins = [&](float e, int f) {
        const bool l2 = (e < d2v) || (e == d2v && f < i2);
        const bool l1 = (e < d1)  || (e == d1  && f < i1);
        const bool l0 = (e < d0)  || (e == d0  && f < i0);
        d2v = l2 ? (l1 ? d1 : e) : d2v;  i2 = l2 ? (l1 ? i1 : f) : i2;
        d1  = l1 ? (l0 ? d0 : e) : d1;   i1 = l1 ? (l0 ? i0 : f) : i1;
        d0  = l0 ? e : d0;               i0 = l0 ? f : i0;
    };
    for (int off = 1; off < 8; off <<= 1) {
        const float e0 = __shfl_xor(d0,  off, 64);
        const float e1 = __shfl_xor(d1,  off, 64);
        const float e2 = __shfl_xor(d2v, off, 64);
        const int   f0 = __shfl_xor(i0,  off, 64);
        const int   f1 = __shfl_xor(i1,  off, 64);
        const int   f2 = __shfl_xor(i2,  off, 64);
        ins(e0, f0);
        ins(e1, f1);
        ins(e2, f2);
    }

    if (s == 0) {
        float w0 = 1.0f / (d0  + 1e-8f);     // IEEE divs, numpy order
        float w1 = 1.0f / (d1  + 1e-8f);
        float w2 = 1.0f / (d2v + 1e-8f);
        const float sum = (w0 + w1) + w2;
        wsI[(size_t)b * NN + qi] = make_int4(i0, i1, i2, 0);
        wsW[(size_t)b * NN + qi] = make_float4(w0 / sum, w1 / sum, w2 / sum, 0.0f);
    }
}

// ===================== kernel 2: row-staged interpolation ====================
// EXACT round-3 kernel — measured-best interp (~24 us). Unchanged.
#define TPB2 512
#define NIB  (BB * (CF + CT) / 2)   // 384 interp blocks (2 rows each)
#define NCB  32                     // copy blocks (4 pf rows each)

__global__ __launch_bounds__(TPB2, 8) void interp_kernel(
    const float* __restrict__ refF,        // [B,256,M]
    const float* __restrict__ refT,        // [B,128,M]
    const float* __restrict__ pf,          // [B,64,N]
    const int4*  __restrict__ wsI,         // [B,N]
    const float4* __restrict__ wsW,        // [B,N]
    float* __restrict__ out)               // [B,320,N] ++ [B,128,N]
{
#pragma clang fp contract(off)
    __shared__ float rowA[MM];             // 16 KB
    __shared__ float rowB[MM];             // 16 KB
    const int tid  = threadIdx.x;
    const int task = blockIdx.x;
    const size_t outT_base = (size_t)BB * (CF + CP) * NN;

    if (task >= NIB) {                     // -------- pf copy blocks --------
        const int t3 = task - NIB;         // 0..31, 4 rows each
        for (int j = 0; j < 4; ++j) {
            const int r  = t3 * 4 + j;
            const int bb = r >> 6;
            const int c  = r & (CP - 1);
            const float4* s4 = (const float4*)(pf + ((size_t)bb * CP + c) * NN);
            float4* d4 = (float4*)(out + ((size_t)bb * (CF + CP) + CF + c) * NN);
            for (int i = tid; i < NN / 4; i += TPB2) d4[i] = s4[i];
        }
        return;                            // block-uniform exit
    }

    const int r0 = task * 2;               // rows r0, r0+1 (same b, same class)
    const float* src0;
    float* dst0;
    int b;
    if (r0 < BB * CF) {                    // interpolated features
        b = r0 >> 8;
        const int c = r0 & (CF - 1);
        src0 = refF + ((size_t)b * CF + c) * MM;
        dst0 = out + ((size_t)b * (CF + CP) + c) * NN;
    } else {                               // interpolated t_embed
        const int r2 = r0 - BB * CF;
        b = r2 >> 7;
        const int c = r2 & (CT - 1);
        src0 = refT + ((size_t)b * CT + c) * MM;
        dst0 = out + outT_base + ((size_t)b * CT + c) * NN;
    }
    const float* src1 = src0 + MM;
    float* dst1 = dst0 + NN;

    for (int i = tid; i < MM / 4; i += TPB2) {
        ((float4*)rowA)[i] = ((const float4*)src0)[i];
        ((float4*)rowB)[i] = ((const float4*)src1)[i];
    }
    __syncthreads();

    const int4*   wi = wsI + (size_t)b * NN;
    const float4* ww = wsW + (size_t)b * NN;

    auto clampi = [](int v) { return v < 0 ? 0 : (v > MM - 1 ? MM - 1 : v); };

    int4   id = wi[tid];
    float4 w  = ww[tid];
    for (int nq = tid; nq < NN; nq += TPB2) {
        const int nq2 = nq + TPB2;
        int4   idn;
        float4 wn;
        if (nq2 < NN) { idn = wi[nq2]; wn = ww[nq2]; }   // prefetch next
        const int a0 = clampi(id.x), a1 = clampi(id.y), a2 = clampi(id.z);
        dst0[nq] = (w.x * rowA[a0] + w.y * rowA[a1]) + w.z * rowA[a2];
        dst1[nq] = (w.x * rowB[a0] + w.y * rowB[a1]) + w.z * rowB[a2];
        id = idn; w = wn;
    }
}

extern "C" void kernel_launch(void* const* d_in, const int* in_sizes, int n_in,
                              void* d_out, int out_size, void* d_ws, size_t ws_size,
                              hipStream_t stream) {
    const float* coords     = (const float*)d_in[0];
    const float* ref_coords = (const float*)d_in[1];
    const float* refF       = (const float*)d_in[2];
    const float* refT       = (const float*)d_in[3];
    const float* pf         = (const float*)d_in[4];
    float* out = (float*)d_out;

    // ws layout (16B-aligned blocks): sR | sJ | sQ | segB | wsI | wsW
    char* w = (char*)d_ws;
    float4* sR   = (float4*)w;                 w += (size_t)BB * MM * sizeof(float4);
    int*    sJ   = (int*)w;                    w += (size_t)BB * MM * sizeof(int);
    int*    sQ   = (int*)w;                    w += (size_t)BB * NN * sizeof(int);
    float2* segB = (float2*)w;                 w += (size_t)BB * NSEG * sizeof(float2);
    int4*   wsI  = (int4*)w;                   w += (size_t)BB * NN * sizeof(int4);
    float4* wsW  = (float4*)w;

    hipLaunchKernelGGL(sort_kernel, dim3(2, BB), dim3(512), 0, stream,
                       coords, ref_coords, sR, sJ, sQ, segB);
    hipLaunchKernelGGL(knn_kernel, dim3(NN / 64, BB), dim3(TPB1), 0, stream,
                       coords, sR, sJ, sQ, segB, wsI, wsW);
    hipLaunchKernelGGL(interp_kernel, dim3(NIB + NCB), dim3(TPB2), 0, stream,
                       refF, refT, pf, wsI, wsW, out);
}